// Round 1
// baseline (68.289 us; speedup 1.0000x reference)
//
#include <hip/hip_runtime.h>
#include <math.h>

#define Bsz 4096
#define Dk 128
#define ROWS_PER_BLOCK 64
#define COL_SPLIT 8
#define COLS_PER_BLOCK (Bsz / COL_SPLIT)        // 512
#define THREADS 256
#define WAVES 4
#define COLS_PER_WAVE (COLS_PER_BLOCK / WAVES)  // 128
#define CT_PER_WAVE (COLS_PER_WAVE / 16)        // 8

typedef __attribute__((ext_vector_type(8))) short short8;
typedef __attribute__((ext_vector_type(4))) float f32x4;

__device__ __forceinline__ unsigned short f2bf(float f) {
  unsigned u = __float_as_uint(f);
  u = (u + 0x7fffu + ((u >> 16) & 1u)) >> 16;   // RNE
  return (unsigned short)u;
}

__device__ __forceinline__ short8 load_frag(const float* p) {
  const float4* q = (const float4*)p;
  float4 v0 = q[0], v1 = q[1];
  short8 r;
  r[0] = (short)f2bf(v0.x); r[1] = (short)f2bf(v0.y);
  r[2] = (short)f2bf(v0.z); r[3] = (short)f2bf(v0.w);
  r[4] = (short)f2bf(v1.x); r[5] = (short)f2bf(v1.y);
  r[6] = (short)f2bf(v1.z); r[7] = (short)f2bf(v1.w);
  return r;
}

// PHASE 0: per-row masked min(pos)/max(neg) partials.
// PHASE 1: per-row masked exp sums partials (uses thresholds from phase 0).
template<int PHASE>
__global__ __launch_bounds__(THREADS, 2)
void gemm_phase(const float* __restrict__ X, const int* __restrict__ labels,
                float* __restrict__ min_part, float* __restrict__ max_part,
                float* __restrict__ pos_part, float* __restrict__ neg_part) {
  const int tid = threadIdx.x;
  const int w  = tid >> 6;
  const int l  = tid & 63;
  const int lg = l >> 4;     // k-group / C row-group
  const int lr = l & 15;     // A row-in-tile / B,C col-in-tile
  const int by = blockIdx.x / COL_SPLIT;
  const int bx = blockIdx.x % COL_SPLIT;
  const int r0 = by * ROWS_PER_BLOCK;
  const int c0 = bx * COLS_PER_BLOCK + w * COLS_PER_WAVE;

  __shared__ float red[2][WAVES][ROWS_PER_BLOCK];
  __shared__ float thr[2][ROWS_PER_BLOCK];

  if (PHASE == 1) {
    if (tid < ROWS_PER_BLOCK) {
      int grow = r0 + tid;
      float mn = INFINITY, mx = -INFINITY;
      for (int b = 0; b < COL_SPLIT; ++b) {
        mn = fminf(mn, min_part[b * Bsz + grow]);
        mx = fmaxf(mx, max_part[b * Bsz + grow]);
      }
      thr[0][tid] = mn;
      thr[1][tid] = mx;
    }
    __syncthreads();
  }

  // A fragments for this block's 64 rows, full K=128, held in registers.
  short8 afrag[4][4];
  for (int rt = 0; rt < 4; ++rt) {
    int row = r0 + rt * 16 + lr;
    for (int ks = 0; ks < 4; ++ks)
      afrag[rt][ks] = load_frag(X + row * Dk + ks * 32 + lg * 8);
  }

  int   labr[16];
  float thr_min[16], thr_max[16];
  for (int rt = 0; rt < 4; ++rt)
    for (int rg = 0; rg < 4; ++rg) {
      int rl = rt * 16 + lg * 4 + rg;      // C-row this lane's acc element holds
      labr[rt * 4 + rg] = labels[r0 + rl];
      if (PHASE == 1) {
        thr_min[rt * 4 + rg] = thr[0][rl];
        thr_max[rt * 4 + rg] = thr[1][rl];
      }
    }

  float acc0[16], acc1[16];
  for (int i = 0; i < 16; ++i) {
    acc0[i] = (PHASE == 0) ? INFINITY  : 0.0f;
    acc1[i] = (PHASE == 0) ? -INFINITY : 0.0f;
  }

  for (int ct = 0; ct < CT_PER_WAVE; ++ct) {
    const int ctc  = c0 + ct * 16;
    const int colv = ctc + lr;
    short8 bfrag[4];
    for (int ks = 0; ks < 4; ++ks)
      bfrag[ks] = load_frag(X + colv * Dk + ks * 32 + lg * 8);
    const int labc = labels[colv];

    for (int rt = 0; rt < 4; ++rt) {
      f32x4 acc = {0.f, 0.f, 0.f, 0.f};
      for (int ks = 0; ks < 4; ++ks)
        acc = __builtin_amdgcn_mfma_f32_16x16x32_bf16(afrag[rt][ks], bfrag[ks], acc, 0, 0, 0);
      // C/D layout (verified): col = lane&15, row = (lane>>4)*4 + reg
      for (int rg = 0; rg < 4; ++rg) {
        float sim  = acc[rg];
        int   idx  = rt * 4 + rg;
        int   rowv = r0 + rt * 16 + lg * 4 + rg;
        bool  eq   = (labc == labr[idx]);
        bool  self = (colv == rowv);
        if (PHASE == 0) {
          if (eq && !self) acc0[idx] = fminf(acc0[idx], sim);
          if (!eq)         acc1[idx] = fmaxf(acc1[idx], sim);
        } else {
          bool pos_keep = eq && !self && (sim - 0.1f < thr_max[idx]);
          bool neg_keep = (!eq) && (sim + 0.1f > thr_min[idx]);
          float arg = pos_keep ? (-2.0f * (sim - 0.5f))
                    : (neg_keep ? (40.0f * (sim - 0.5f)) : -INFINITY);
          float e = __expf(arg);   // exp(-inf) = 0
          if (pos_keep) acc0[idx] += e;
          if (neg_keep) acc1[idx] += e;
        }
      }
    }
  }

  // reduce across the 16 col-lanes sharing each row
  for (int i = 0; i < 16; ++i) {
    for (int m = 1; m < 16; m <<= 1) {
      float o0 = __shfl_xor(acc0[i], m, 64);
      float o1 = __shfl_xor(acc1[i], m, 64);
      if (PHASE == 0) { acc0[i] = fminf(acc0[i], o0); acc1[i] = fmaxf(acc1[i], o1); }
      else            { acc0[i] += o0;               acc1[i] += o1; }
    }
  }
  if (lr == 0) {
    for (int i = 0; i < 16; ++i) {
      int rt = i >> 2, rg = i & 3;
      int rl = rt * 16 + lg * 4 + rg;
      red[0][w][rl] = acc0[i];
      red[1][w][rl] = acc1[i];
    }
  }
  __syncthreads();

  if (tid < ROWS_PER_BLOCK) {
    if (PHASE == 0) {
      float v0 = INFINITY, v1 = -INFINITY;
      for (int ww = 0; ww < WAVES; ++ww) {
        v0 = fminf(v0, red[0][ww][tid]);
        v1 = fmaxf(v1, red[1][ww][tid]);
      }
      min_part[bx * Bsz + r0 + tid] = v0;
      max_part[bx * Bsz + r0 + tid] = v1;
    } else {
      float v0 = 0.f, v1 = 0.f;
      for (int ww = 0; ww < WAVES; ++ww) {
        v0 += red[0][ww][tid];
        v1 += red[1][ww][tid];
      }
      pos_part[bx * Bsz + r0 + tid] = v0;
      neg_part[bx * Bsz + r0 + tid] = v1;
    }
  }
}

__global__ __launch_bounds__(1024)
void finalize(const float* __restrict__ pos_part, const float* __restrict__ neg_part,
              float* __restrict__ out) {
  int tid = threadIdx.x;
  float s = 0.f, c = 0.f;
  for (int r = tid; r < Bsz; r += 1024) {
    float ps = 0.f, ns = 0.f;
    for (int b = 0; b < COL_SPLIT; ++b) {
      ps += pos_part[b * Bsz + r];
      ns += neg_part[b * Bsz + r];
    }
    if (ps > 0.f && ns > 0.f) {   // valid row: kept-positives AND kept-negatives exist
      s += log1pf(ps) * 0.5f + log1pf(ns) * 0.025f;
      c += 1.f;
    }
  }
  for (int m = 1; m < 64; m <<= 1) {
    s += __shfl_xor(s, m, 64);
    c += __shfl_xor(c, m, 64);
  }
  __shared__ float rs[16], rc[16];
  int w = tid >> 6, lzero = tid & 63;
  if (lzero == 0) { rs[w] = s; rc[w] = c; }
  __syncthreads();
  if (tid == 0) {
    float ts = 0.f, tc = 0.f;
    for (int i = 0; i < 16; ++i) { ts += rs[i]; tc += rc[i]; }
    out[0] = ts / fmaxf(tc, 1.0f);
  }
}

extern "C" void kernel_launch(void* const* d_in, const int* in_sizes, int n_in,
                              void* d_out, int out_size, void* d_ws, size_t ws_size,
                              hipStream_t stream) {
  const float* X      = (const float*)d_in[0];
  const int*   labels = (const int*)d_in[1];
  float* ws = (float*)d_ws;
  float* min_part = ws + 0 * COL_SPLIT * Bsz;
  float* max_part = ws + 1 * COL_SPLIT * Bsz;
  float* pos_part = ws + 2 * COL_SPLIT * Bsz;
  float* neg_part = ws + 3 * COL_SPLIT * Bsz;   // total 512 KB of d_ws

  dim3 grid(64 * COL_SPLIT);   // 64 row-blocks x 8 col-splits
  gemm_phase<0><<<grid, THREADS, 0, stream>>>(X, labels, min_part, max_part, pos_part, neg_part);
  gemm_phase<1><<<grid, THREADS, 0, stream>>>(X, labels, min_part, max_part, pos_part, neg_part);
  finalize<<<1, 1024, 0, stream>>>(pos_part, neg_part, (float*)d_out);
}

// Round 2
// 55.706 us; speedup vs baseline: 1.2259x; 1.2259x over previous
//
#include <hip/hip_runtime.h>
#include <math.h>

#define Bsz 4096
#define Dk 128
#define ROWS_PER_BLOCK 64
#define COL_SPLIT 8
#define COLS_PER_BLOCK (Bsz / COL_SPLIT)        // 512
#define THREADS 256
#define WAVES 4
#define COLS_PER_WAVE (COLS_PER_BLOCK / WAVES)  // 128
#define CT_PER_WAVE (COLS_PER_WAVE / 16)        // 8

typedef __attribute__((ext_vector_type(8))) short short8;
typedef __attribute__((ext_vector_type(4))) float f32x4;
typedef _Float16 half8 __attribute__((ext_vector_type(8)));

__device__ __forceinline__ unsigned short f2bf(float f) {
  unsigned u = __float_as_uint(f);
  u = (u + 0x7fffu + ((u >> 16) & 1u)) >> 16;   // RNE
  return (unsigned short)u;
}

// X fp32 [4096][128] -> bf16 [4096][128], one shot.
__global__ __launch_bounds__(256)
void convert_kernel(const float* __restrict__ X, short* __restrict__ Xb) {
  int i = blockIdx.x * 256 + threadIdx.x;     // 65536 threads x 8 elems
  const float4* q = (const float4*)X + i * 2;
  float4 v0 = q[0], v1 = q[1];
  short8 r;
  r[0] = (short)f2bf(v0.x); r[1] = (short)f2bf(v0.y);
  r[2] = (short)f2bf(v0.z); r[3] = (short)f2bf(v0.w);
  r[4] = (short)f2bf(v1.x); r[5] = (short)f2bf(v1.y);
  r[6] = (short)f2bf(v1.z); r[7] = (short)f2bf(v1.w);
  ((short8*)Xb)[i] = r;
}

// Phase A: one GEMM pass. Produces per-row min(pos)/max(neg) partials AND
// the encoded fp16 sim matrix: self -> 8.0, eq -> sim+4, else sim.
__global__ __launch_bounds__(THREADS, 2)
void phaseA(const short* __restrict__ Xb, const int* __restrict__ labels,
            _Float16* __restrict__ sim16,
            float* __restrict__ min_part, float* __restrict__ max_part) {
  const int tid = threadIdx.x;
  const int w  = tid >> 6;
  const int l  = tid & 63;
  const int lg = l >> 4;     // k-group / C row-group
  const int lr = l & 15;     // A row-in-tile / B,C col-in-tile
  const int by = blockIdx.x / COL_SPLIT;
  const int bx = blockIdx.x % COL_SPLIT;
  const int r0 = by * ROWS_PER_BLOCK;
  const int c0 = bx * COLS_PER_BLOCK + w * COLS_PER_WAVE;

  __shared__ float red[2][WAVES][ROWS_PER_BLOCK];

  // A fragments: 64 rows x K=128, bf16, in registers.
  short8 afrag[4][4];
  for (int rt = 0; rt < 4; ++rt) {
    int row = r0 + rt * 16 + lr;
    for (int ks = 0; ks < 4; ++ks)
      afrag[rt][ks] = *(const short8*)(Xb + row * Dk + ks * 32 + lg * 8);
  }

  int labr[16];
  for (int rt = 0; rt < 4; ++rt)
    for (int rg = 0; rg < 4; ++rg)
      labr[rt * 4 + rg] = labels[r0 + rt * 16 + lg * 4 + rg];

  float mn[16], mx[16];
  for (int i = 0; i < 16; ++i) { mn[i] = INFINITY; mx[i] = -INFINITY; }

  for (int ct = 0; ct < CT_PER_WAVE; ++ct) {
    const int ctc  = c0 + ct * 16;
    const int colv = ctc + lr;
    short8 bfrag[4];
    for (int ks = 0; ks < 4; ++ks)
      bfrag[ks] = *(const short8*)(Xb + colv * Dk + ks * 32 + lg * 8);
    const int labc = labels[colv];

    for (int rt = 0; rt < 4; ++rt) {
      f32x4 acc = {0.f, 0.f, 0.f, 0.f};
      for (int ks = 0; ks < 4; ++ks)
        acc = __builtin_amdgcn_mfma_f32_16x16x32_bf16(afrag[rt][ks], bfrag[ks], acc, 0, 0, 0);
      const bool diag = (ctc == r0 + rt * 16);   // wave-uniform
      // C/D layout (verified): col = lane&15, row = (lane>>4)*4 + reg
      for (int rg = 0; rg < 4; ++rg) {
        int   idx  = rt * 4 + rg;
        float s    = acc[rg];
        bool  eq   = (labc == labr[idx]);
        bool  self = diag && (lr == lg * 4 + rg);
        if (eq && !self) mn[idx] = fminf(mn[idx], s);
        if (!eq)         mx[idx] = fmaxf(mx[idx], s);
        float enc = eq ? s + 4.0f : s;
        if (self) enc = 8.0f;
        int rowv = r0 + rt * 16 + lg * 4 + rg;
        sim16[rowv * Bsz + colv] = (_Float16)enc;
      }
    }
  }

  // reduce min/max across the 16 col-lanes sharing each row
  for (int i = 0; i < 16; ++i) {
    for (int m = 1; m < 16; m <<= 1) {
      float o0 = __shfl_xor(mn[i], m, 64);
      float o1 = __shfl_xor(mx[i], m, 64);
      mn[i] = fminf(mn[i], o0);
      mx[i] = fmaxf(mx[i], o1);
    }
  }
  if (lr == 0) {
    for (int i = 0; i < 16; ++i) {
      int rt = i >> 2, rg = i & 3;
      red[0][w][rt * 16 + lg * 4 + rg] = mn[i];
      red[1][w][rt * 16 + lg * 4 + rg] = mx[i];
    }
  }
  __syncthreads();

  if (tid < ROWS_PER_BLOCK) {
    float v0 = INFINITY, v1 = -INFINITY;
    for (int ww = 0; ww < WAVES; ++ww) {
      v0 = fminf(v0, red[0][ww][tid]);
      v1 = fmaxf(v1, red[1][ww][tid]);
    }
    min_part[bx * Bsz + r0 + tid] = v0;
    max_part[bx * Bsz + r0 + tid] = v1;
  }
}

// Phase B: stream the encoded sim matrix; one row per wave.
__global__ __launch_bounds__(THREADS)
void phaseB(const _Float16* __restrict__ sim16, const float* __restrict__ max_part,
            float* __restrict__ pos_sum, float* __restrict__ neg_sum) {
  const int w = threadIdx.x >> 6;
  const int l = threadIdx.x & 63;
  const int r = blockIdx.x * WAVES + w;

  float thr = -INFINITY;
  for (int b = 0; b < COL_SPLIT; ++b) thr = fmaxf(thr, max_part[b * Bsz + r]);
  const float thr41 = thr + 4.1f;   // sim-0.1 < thr  <=>  v < thr+4.1 (v=sim+4)

  float ap = 0.f, an = 0.f;
  const half8* base = (const half8*)(sim16 + r * Bsz);
  for (int ch = 0; ch < 8; ++ch) {
    half8 h = base[ch * 64 + l];
    for (int j = 0; j < 8; ++j) {
      float v  = (float)h[j];
      bool  eq = v > 2.0f;
      bool  kp = eq && (v < thr41);
      float argp = fmaf(v, -2.88539008f, 12.98425537f);   // -2*(v-4.5)*log2e
      float argn = fmaf(v, 57.70780163f, -28.85390082f);  // 40*(v-0.5)*log2e
      float e = exp2f(kp ? argp : argn);   // dead-lane inf discarded by selects
      ap += kp ? e : 0.0f;
      an += eq ? 0.0f : e;
    }
  }
  for (int m = 1; m < 64; m <<= 1) {
    ap += __shfl_xor(ap, m, 64);
    an += __shfl_xor(an, m, 64);
  }
  if (l == 0) { pos_sum[r] = ap; neg_sum[r] = an; }
}

__global__ __launch_bounds__(1024)
void finalize(const float* __restrict__ min_part, const float* __restrict__ max_part,
              const float* __restrict__ pos_sum, const float* __restrict__ neg_sum,
              float* __restrict__ out) {
  int tid = threadIdx.x;
  float s = 0.f, c = 0.f;
  for (int r = tid; r < Bsz; r += 1024) {
    float mn = INFINITY, mx = -INFINITY;
    for (int b = 0; b < COL_SPLIT; ++b) {
      mn = fminf(mn, min_part[b * Bsz + r]);
      mx = fmaxf(mx, max_part[b * Bsz + r]);
    }
    bool valid = (mx + 0.1f > mn) && (mn - 0.1f < mx);  // any-pos-kept && any-neg-kept
    if (valid) {
      s += log1pf(pos_sum[r]) * 0.5f + log1pf(neg_sum[r]) * 0.025f;
      c += 1.f;
    }
  }
  for (int m = 1; m < 64; m <<= 1) {
    s += __shfl_xor(s, m, 64);
    c += __shfl_xor(c, m, 64);
  }
  __shared__ float rs[16], rc[16];
  int w = tid >> 6, lz = tid & 63;
  if (lz == 0) { rs[w] = s; rc[w] = c; }
  __syncthreads();
  if (tid == 0) {
    float ts = 0.f, tc = 0.f;
    for (int i = 0; i < 16; ++i) { ts += rs[i]; tc += rc[i]; }
    out[0] = ts / fmaxf(tc, 1.0f);
  }
}

extern "C" void kernel_launch(void* const* d_in, const int* in_sizes, int n_in,
                              void* d_out, int out_size, void* d_ws, size_t ws_size,
                              hipStream_t stream) {
  const float* X      = (const float*)d_in[0];
  const int*   labels = (const int*)d_in[1];

  char* ws = (char*)d_ws;
  _Float16* sim16    = (_Float16*)(ws);                               // 32 MB
  short*    Xb       = (short*)(ws + 33554432);                       // 1 MB
  float*    min_part = (float*)(ws + 33554432 + 1048576);             // 128 KB
  float*    max_part = (float*)(ws + 33554432 + 1048576 + 131072);    // 128 KB
  float*    pos_sum  = (float*)(ws + 33554432 + 1048576 + 262144);    // 16 KB
  float*    neg_sum  = (float*)(ws + 33554432 + 1048576 + 278528);    // 16 KB

  convert_kernel<<<256, 256, 0, stream>>>(X, Xb);
  phaseA<<<64 * COL_SPLIT, THREADS, 0, stream>>>(Xb, labels, sim16, min_part, max_part);
  phaseB<<<Bsz / WAVES, THREADS, 0, stream>>>(sim16, max_part, pos_sum, neg_sum);
  finalize<<<1, 1024, 0, stream>>>(min_part, max_part, pos_sum, neg_sum, (float*)d_out);
}

// Round 3
// 55.287 us; speedup vs baseline: 1.2352x; 1.0076x over previous
//
#include <hip/hip_runtime.h>
#include <math.h>

#define Bsz 4096
#define Dk 128
#define ROWS_PER_BLOCK 32
#define COL_SPLIT 8
#define COLS_PER_BLOCK (Bsz / COL_SPLIT)        // 512
#define THREADS 256
#define WAVES 4
#define COLS_PER_WAVE (COLS_PER_BLOCK / WAVES)  // 128
#define CT_PER_WAVE (COLS_PER_WAVE / 16)        // 8
#define RT 2                                    // 32 rows = 2 x 16-row tiles

typedef __attribute__((ext_vector_type(8))) short short8;
typedef __attribute__((ext_vector_type(4))) float f32x4;
typedef _Float16 half8 __attribute__((ext_vector_type(8)));
typedef _Float16 half4 __attribute__((ext_vector_type(4)));

__device__ __forceinline__ unsigned short f2bf(float f) {
  unsigned u = __float_as_uint(f);
  u = (u + 0x7fffu + ((u >> 16) & 1u)) >> 16;   // RNE
  return (unsigned short)u;
}

// X fp32 [4096][128] -> bf16 [4096][128], one shot.
__global__ __launch_bounds__(256)
void convert_kernel(const float* __restrict__ X, short* __restrict__ Xb) {
  int i = blockIdx.x * 256 + threadIdx.x;     // 65536 threads x 8 elems
  const float4* q = (const float4*)X + i * 2;
  float4 v0 = q[0], v1 = q[1];
  short8 r;
  r[0] = (short)f2bf(v0.x); r[1] = (short)f2bf(v0.y);
  r[2] = (short)f2bf(v0.z); r[3] = (short)f2bf(v0.w);
  r[4] = (short)f2bf(v1.x); r[5] = (short)f2bf(v1.y);
  r[6] = (short)f2bf(v1.z); r[7] = (short)f2bf(v1.w);
  ((short8*)Xb)[i] = r;
}

// Phase A: one GEMM pass. Per-row min(pos)/max(neg) partials AND the encoded
// fp16 sim matrix: self -> 8.0, eq -> sim+4, else sim. enc is exactly
// symmetric (bitwise: dot(a,b)==dot(b,a) in MFMA, eq/self symmetric), so we
// store each tile TRANSPOSED: the 4 acc regs (4 consecutive rows) become 4
// consecutive fp16 at sim16[col][row..row+3] -> one packed 8B store.
__global__ __launch_bounds__(THREADS, 4)
void phaseA(const short* __restrict__ Xb, const int* __restrict__ labels,
            _Float16* __restrict__ sim16,
            float* __restrict__ min_part, float* __restrict__ max_part) {
  const int tid = threadIdx.x;
  const int w  = tid >> 6;
  const int l  = tid & 63;
  const int lg = l >> 4;     // k-group / C row-group
  const int lr = l & 15;     // A row-in-tile / B,C col-in-tile
  const int by = blockIdx.x / COL_SPLIT;
  const int bx = blockIdx.x % COL_SPLIT;
  const int r0 = by * ROWS_PER_BLOCK;
  const int c0 = bx * COLS_PER_BLOCK + w * COLS_PER_WAVE;

  __shared__ float red[2][WAVES][ROWS_PER_BLOCK];

  // A fragments: 32 rows x K=128, bf16, in registers (32 VGPR).
  short8 afrag[RT][4];
  for (int rt = 0; rt < RT; ++rt) {
    int row = r0 + rt * 16 + lr;
    for (int ks = 0; ks < 4; ++ks)
      afrag[rt][ks] = *(const short8*)(Xb + row * Dk + ks * 32 + lg * 8);
  }

  int labr[RT * 4];
  for (int rt = 0; rt < RT; ++rt)
    for (int rg = 0; rg < 4; ++rg)
      labr[rt * 4 + rg] = labels[r0 + rt * 16 + lg * 4 + rg];

  float mn[RT * 4], mx[RT * 4];
  for (int i = 0; i < RT * 4; ++i) { mn[i] = INFINITY; mx[i] = -INFINITY; }

  for (int ct = 0; ct < CT_PER_WAVE; ++ct) {
    const int ctc  = c0 + ct * 16;
    const int colv = ctc + lr;
    short8 bfrag[4];
    for (int ks = 0; ks < 4; ++ks)
      bfrag[ks] = *(const short8*)(Xb + colv * Dk + ks * 32 + lg * 8);
    const int labc = labels[colv];

    for (int rt = 0; rt < RT; ++rt) {
      f32x4 acc = {0.f, 0.f, 0.f, 0.f};
      for (int ks = 0; ks < 4; ++ks)
        acc = __builtin_amdgcn_mfma_f32_16x16x32_bf16(afrag[rt][ks], bfrag[ks], acc, 0, 0, 0);
      const bool diag = (ctc == r0 + rt * 16);   // wave-uniform
      half4 h;
      // C/D layout (verified): col = lane&15, row = (lane>>4)*4 + reg
      for (int rg = 0; rg < 4; ++rg) {
        int   idx  = rt * 4 + rg;
        float s    = acc[rg];
        bool  eq   = (labc == labr[idx]);
        bool  self = diag && (lr == lg * 4 + rg);
        if (eq && !self) mn[idx] = fminf(mn[idx], s);
        if (!eq)         mx[idx] = fmaxf(mx[idx], s);
        float enc = eq ? s + 4.0f : s;
        if (self) enc = 8.0f;
        h[rg] = (_Float16)enc;
      }
      // transposed packed store: sim16[colv][r0+rt*16+lg*4 .. +3]
      *(half4*)(sim16 + (size_t)colv * Bsz + r0 + rt * 16 + lg * 4) = h;
    }
  }

  // reduce min/max across the 16 col-lanes sharing each row
  for (int i = 0; i < RT * 4; ++i) {
    for (int m = 1; m < 16; m <<= 1) {
      float o0 = __shfl_xor(mn[i], m, 64);
      float o1 = __shfl_xor(mx[i], m, 64);
      mn[i] = fminf(mn[i], o0);
      mx[i] = fmaxf(mx[i], o1);
    }
  }
  if (lr == 0) {
    for (int i = 0; i < RT * 4; ++i) {
      int rt = i >> 2, rg = i & 3;
      red[0][w][rt * 16 + lg * 4 + rg] = mn[i];
      red[1][w][rt * 16 + lg * 4 + rg] = mx[i];
    }
  }
  __syncthreads();

  if (tid < ROWS_PER_BLOCK) {
    float v0 = INFINITY, v1 = -INFINITY;
    for (int ww = 0; ww < WAVES; ++ww) {
      v0 = fminf(v0, red[0][ww][tid]);
      v1 = fmaxf(v1, red[1][ww][tid]);
    }
    min_part[bx * Bsz + r0 + tid] = v0;
    max_part[bx * Bsz + r0 + tid] = v1;
  }
}

// Phase B: stream the encoded sim matrix; one row per wave.
// Emits row_loss (0 if invalid) and valid flag.
__global__ __launch_bounds__(THREADS)
void phaseB(const _Float16* __restrict__ sim16,
            const float* __restrict__ min_part, const float* __restrict__ max_part,
            float* __restrict__ row_loss, float* __restrict__ row_valid) {
  const int w = threadIdx.x >> 6;
  const int l = threadIdx.x & 63;
  const int r = blockIdx.x * WAVES + w;

  float mnr = INFINITY, mxr = -INFINITY;
  for (int b = 0; b < COL_SPLIT; ++b) {
    mnr = fminf(mnr, min_part[b * Bsz + r]);
    mxr = fmaxf(mxr, max_part[b * Bsz + r]);
  }
  const float thr41 = mxr + 4.1f;   // sim-0.1 < max_neg  <=>  v < thr41 (v=sim+4)

  float ap = 0.f, an = 0.f;
  const half8* base = (const half8*)(sim16 + (size_t)r * Bsz);
#pragma unroll
  for (int ch = 0; ch < 8; ++ch) {
    half8 h = base[ch * 64 + l];
#pragma unroll
    for (int j = 0; j < 8; ++j) {
      float v  = (float)h[j];
      bool  eq = v > 2.0f;
      bool  kp = eq && (v < thr41);
      float argp = fmaf(v, -2.88539008f, 12.98425537f);   // -2*(v-4.5)*log2e
      float argn = fmaf(v, 57.70780163f, -28.85390082f);  // 40*(v-0.5)*log2e
      float e = exp2f(kp ? argp : argn);
      ap += kp ? e : 0.0f;
      an += eq ? 0.0f : e;
    }
  }
  for (int m = 1; m < 64; m <<= 1) {
    ap += __shfl_xor(ap, m, 64);
    an += __shfl_xor(an, m, 64);
  }
  if (l == 0) {
    bool valid = (mxr + 0.1f > mnr) && (mnr - 0.1f < mxr);  // any pos kept && any neg kept
    row_loss[r]  = valid ? (log1pf(ap) * 0.5f + log1pf(an) * 0.025f) : 0.0f;
    row_valid[r] = valid ? 1.0f : 0.0f;
  }
}

__global__ __launch_bounds__(1024)
void finalize(const float* __restrict__ row_loss, const float* __restrict__ row_valid,
              float* __restrict__ out) {
  int tid = threadIdx.x;
  float s = 0.f, c = 0.f;
  for (int r = tid; r < Bsz; r += 1024) {
    s += row_loss[r];
    c += row_valid[r];
  }
  for (int m = 1; m < 64; m <<= 1) {
    s += __shfl_xor(s, m, 64);
    c += __shfl_xor(c, m, 64);
  }
  __shared__ float rs[16], rc[16];
  int w = tid >> 6, lz = tid & 63;
  if (lz == 0) { rs[w] = s; rc[w] = c; }
  __syncthreads();
  if (tid == 0) {
    float ts = 0.f, tc = 0.f;
    for (int i = 0; i < 16; ++i) { ts += rs[i]; tc += rc[i]; }
    out[0] = ts / fmaxf(tc, 1.0f);
  }
}

extern "C" void kernel_launch(void* const* d_in, const int* in_sizes, int n_in,
                              void* d_out, int out_size, void* d_ws, size_t ws_size,
                              hipStream_t stream) {
  const float* X      = (const float*)d_in[0];
  const int*   labels = (const int*)d_in[1];

  char* ws = (char*)d_ws;
  _Float16* sim16    = (_Float16*)(ws);                               // 32 MB
  short*    Xb       = (short*)(ws + 33554432);                       // 1 MB
  float*    min_part = (float*)(ws + 33554432 + 1048576);             // 128 KB
  float*    max_part = (float*)(ws + 33554432 + 1048576 + 131072);    // 128 KB
  float*    row_loss = (float*)(ws + 33554432 + 1048576 + 262144);    // 16 KB
  float*    row_valid= (float*)(ws + 33554432 + 1048576 + 278528);    // 16 KB

  convert_kernel<<<256, 256, 0, stream>>>(X, Xb);
  phaseA<<<(Bsz / ROWS_PER_BLOCK) * COL_SPLIT, THREADS, 0, stream>>>(Xb, labels, sim16, min_part, max_part);
  phaseB<<<Bsz / WAVES, THREADS, 0, stream>>>(sim16, min_part, max_part, row_loss, row_valid);
  finalize<<<1, 1024, 0, stream>>>(row_loss, row_valid, (float*)d_out);
}